// Round 1
// baseline (290.326 us; speedup 1.0000x reference)
//
#include <hip/hip_runtime.h>
#include <hip/hip_bf16.h>

#define NB 4
#define NT 4096
#define NE 768
#define NH 64

using bf16 = __hip_bfloat16;
typedef __attribute__((ext_vector_type(8))) short bf16x8;
typedef __attribute__((ext_vector_type(4))) float f32x4;

__device__ inline short f2bfs(float f) {
  bf16 h = __float2bfloat16(f);
  return __builtin_bit_cast(short, h);
}

// ---------------- kernel 0: W^T (bf16) precompute -------------------------
// Wt[m][h][e], m: 0=Wk, 1=Wq(×0.125 folded), 2=Wv
__global__ void k_wt(const float* __restrict__ Wk, const float* __restrict__ Wq,
                     const float* __restrict__ Wv, bf16* __restrict__ Wt) {
  int idx = blockIdx.x * 256 + threadIdx.x;
  if (idx >= 3 * NH * NE) return;
  int m = idx / (NH * NE);
  int r = idx - m * NH * NE;
  int h = r / NE;
  int e = r - h * NE;
  const float* W = (m == 0) ? Wk : ((m == 1) ? Wq : Wv);
  float v = W[e * NH + h];
  if (m == 1) v *= 0.125f;  // softmax scale folded into Q projection
  Wt[idx] = __float2bfloat16(v);
}

// ---------------- kernel 1: Q/K/V projections (MFMA) ----------------------
// grid (256, 3), block 256 (4 waves). Wave = 16-row stripe of x.
// m==0 -> K[t][h], m==1 -> Q[t][h] (scaled), m==2 -> Vt[b][h][t]
__global__ __launch_bounds__(256) void k_proj(const float* __restrict__ x,
                                              const bf16* __restrict__ Wt,
                                              bf16* __restrict__ Q,
                                              bf16* __restrict__ K,
                                              bf16* __restrict__ Vt) {
  const int wave = threadIdx.x >> 6;
  const int lane = threadIdx.x & 63;
  const int lr = lane & 15;   // A row / B col
  const int lk = lane >> 4;   // k sub-block
  const int m = blockIdx.y;
  const int stripe = blockIdx.x * 4 + wave;  // 0..1023
  const int row0 = stripe * 16;
  const bf16* Wp = Wt + m * (NH * NE);

  f32x4 acc[4];
#pragma unroll
  for (int cb = 0; cb < 4; ++cb)
#pragma unroll
    for (int r = 0; r < 4; ++r) acc[cb][r] = 0.f;

  const float* xrow = x + (size_t)(row0 + lr) * NE;
#pragma unroll 4
  for (int ks = 0; ks < NE / 32; ++ks) {
    const int e0 = ks * 32 + lk * 8;
    float4 a0 = *reinterpret_cast<const float4*>(xrow + e0);
    float4 a1 = *reinterpret_cast<const float4*>(xrow + e0 + 4);
    bf16x8 af;
    af[0] = f2bfs(a0.x); af[1] = f2bfs(a0.y); af[2] = f2bfs(a0.z); af[3] = f2bfs(a0.w);
    af[4] = f2bfs(a1.x); af[5] = f2bfs(a1.y); af[6] = f2bfs(a1.z); af[7] = f2bfs(a1.w);
#pragma unroll
    for (int cb = 0; cb < 4; ++cb) {
      bf16x8 bfr = *reinterpret_cast<const bf16x8*>(Wp + (cb * 16 + lr) * NE + e0);
      acc[cb] = __builtin_amdgcn_mfma_f32_16x16x32_bf16(af, bfr, acc[cb], 0, 0, 0);
    }
  }

  const int trow = row0 + lk * 4;  // C/D: row=(lane>>4)*4+reg, col=lane&15
  if (m == 0) {
#pragma unroll
    for (int cb = 0; cb < 4; ++cb) {
      const int h = cb * 16 + lr;
#pragma unroll
      for (int r = 0; r < 4; ++r)
        K[(size_t)(trow + r) * NH + h] = __float2bfloat16(acc[cb][r]);
    }
  } else if (m == 1) {
#pragma unroll
    for (int cb = 0; cb < 4; ++cb) {
      const int h = cb * 16 + lr;
#pragma unroll
      for (int r = 0; r < 4; ++r)
        Q[(size_t)(trow + r) * NH + h] = __float2bfloat16(acc[cb][r]);
    }
  } else {
    const int b = trow >> 12;
    const int t = trow & (NT - 1);
#pragma unroll
    for (int cb = 0; cb < 4; ++cb) {
      const int h = cb * 16 + lr;
      ushort4 pk;
      pk.x = (unsigned short)f2bfs(acc[cb][0]);
      pk.y = (unsigned short)f2bfs(acc[cb][1]);
      pk.z = (unsigned short)f2bfs(acc[cb][2]);
      pk.w = (unsigned short)f2bfs(acc[cb][3]);
      *reinterpret_cast<ushort4*>(Vt + (size_t)(b * NH + h) * NT + t) = pk;
    }
  }
}

// ---------------- kernel 2: causal flash attention ------------------------
// 1024 single-wave blocks; block gid -> batch b=gid&3, q-stripe s=255-(gid>>2)
// (descending work for load balance). Wave owns 16 q rows; streams 64-key
// KV tiles from L2; online softmax; P via small LDS to re-layout for PV MFMA.
__global__ __launch_bounds__(64) void k_attn(const bf16* __restrict__ Q,
                                             const bf16* __restrict__ K,
                                             const bf16* __restrict__ Vt,
                                             float* __restrict__ out) {
  __shared__ __align__(16) bf16 Pl[16][72];  // +8 pad: breaks bank aliasing
  const int lane = threadIdx.x;
  const int lr = lane & 15;
  const int lk = lane >> 4;
  const int gid = blockIdx.x;
  const int s = 255 - (gid >> 2);
  const int b = gid & 3;
  const int qbase = s * 16;

  const bf16* Qb = Q + (size_t)(b * NT + qbase) * NH;
  const bf16* Kb = K + (size_t)b * NT * NH;
  const bf16* Vb = Vt + (size_t)b * NH * NT;

  bf16x8 qf[2];
#pragma unroll
  for (int ks = 0; ks < 2; ++ks)
    qf[ks] = *reinterpret_cast<const bf16x8*>(Qb + lr * NH + ks * 32 + lk * 8);

  f32x4 o[4];
#pragma unroll
  for (int cb = 0; cb < 4; ++cb)
#pragma unroll
    for (int r = 0; r < 4; ++r) o[cb][r] = 0.f;
  float mrow[4], lsum[4];
#pragma unroll
  for (int r = 0; r < 4; ++r) { mrow[r] = -1e30f; lsum[r] = 0.f; }

  const int ktmax = s >> 2;
  for (int kt = 0; kt <= ktmax; ++kt) {
    const int k0 = kt * 64;
    // ---- S = Q K^T over this 64-key tile
    f32x4 sa[4];
#pragma unroll
    for (int cb = 0; cb < 4; ++cb)
#pragma unroll
      for (int r = 0; r < 4; ++r) sa[cb][r] = 0.f;
#pragma unroll
    for (int ks = 0; ks < 2; ++ks)
#pragma unroll
      for (int cb = 0; cb < 4; ++cb) {
        bf16x8 kf = *reinterpret_cast<const bf16x8*>(
            Kb + (size_t)(k0 + cb * 16 + lr) * NH + ks * 32 + lk * 8);
        sa[cb] = __builtin_amdgcn_mfma_f32_16x16x32_bf16(qf[ks], kf, sa[cb], 0, 0, 0);
      }
    // ---- causal mask (only the diagonal tile needs it)
    if (kt == ktmax) {
#pragma unroll
      for (int cb = 0; cb < 4; ++cb)
#pragma unroll
        for (int r = 0; r < 4; ++r) {
          const int kg = k0 + cb * 16 + lr;
          const int qg = qbase + lk * 4 + r;
          if (kg > qg) sa[cb][r] = -1e30f;
        }
    }
    // ---- online softmax (rows live in 16-lane groups; reduce via shfl_xor)
    float pm[4];
#pragma unroll
    for (int r = 0; r < 4; ++r)
      pm[r] = fmaxf(fmaxf(sa[0][r], sa[1][r]), fmaxf(sa[2][r], sa[3][r]));
#pragma unroll
    for (int msk = 1; msk < 16; msk <<= 1)
#pragma unroll
      for (int r = 0; r < 4; ++r)
        pm[r] = fmaxf(pm[r], __shfl_xor(pm[r], msk));
    float alpha[4], rs[4];
#pragma unroll
    for (int r = 0; r < 4; ++r) {
      const float mn = fmaxf(mrow[r], pm[r]);
      alpha[r] = __expf(mrow[r] - mn);
      mrow[r] = mn;
      rs[r] = 0.f;
    }
    __syncthreads();  // prior PV A-frag reads complete before overwrite
#pragma unroll
    for (int cb = 0; cb < 4; ++cb)
#pragma unroll
      for (int r = 0; r < 4; ++r) {
        const float p = __expf(sa[cb][r] - mrow[r]);
        rs[r] += p;
        Pl[lk * 4 + r][cb * 16 + lr] = __float2bfloat16(p);
      }
#pragma unroll
    for (int msk = 1; msk < 16; msk <<= 1)
#pragma unroll
      for (int r = 0; r < 4; ++r) rs[r] += __shfl_xor(rs[r], msk);
#pragma unroll
    for (int r = 0; r < 4; ++r) lsum[r] = lsum[r] * alpha[r] + rs[r];
#pragma unroll
    for (int cb = 0; cb < 4; ++cb)
#pragma unroll
      for (int r = 0; r < 4; ++r) o[cb][r] *= alpha[r];
    __syncthreads();  // P visible
    // ---- O += P V  (A-frags from LDS, B-frags = Vt rows, contiguous)
    bf16x8 pa[2];
#pragma unroll
    for (int ks = 0; ks < 2; ++ks)
      pa[ks] = *reinterpret_cast<const bf16x8*>(&Pl[lr][ks * 32 + lk * 8]);
#pragma unroll
    for (int ks = 0; ks < 2; ++ks)
#pragma unroll
      for (int cb = 0; cb < 4; ++cb) {
        bf16x8 vf = *reinterpret_cast<const bf16x8*>(
            Vb + (size_t)(cb * 16 + lr) * NT + k0 + ks * 32 + lk * 8);
        o[cb] = __builtin_amdgcn_mfma_f32_16x16x32_bf16(pa[ks], vf, o[cb], 0, 0, 0);
      }
  }

  float* ob = out + (size_t)(b * NT + qbase) * NH;
#pragma unroll
  for (int cb = 0; cb < 4; ++cb) {
    const int h = cb * 16 + lr;
#pragma unroll
    for (int r = 0; r < 4; ++r)
      ob[(lk * 4 + r) * NH + h] = o[cb][r] / lsum[r];
  }
}

// ---------------- launcher ------------------------------------------------
extern "C" void kernel_launch(void* const* d_in, const int* in_sizes, int n_in,
                              void* d_out, int out_size, void* d_ws, size_t ws_size,
                              hipStream_t stream) {
  const float* x  = (const float*)d_in[0];
  const float* Wk = (const float*)d_in[1];
  const float* Wq = (const float*)d_in[2];
  const float* Wv = (const float*)d_in[3];
  float* out = (float*)d_out;

  char* ws = (char*)d_ws;
  const size_t off_wt = 0;
  const size_t sz_wt  = (size_t)3 * NH * NE * sizeof(bf16);     // 294912
  const size_t off_q  = off_wt + sz_wt;
  const size_t sz_qkv = (size_t)NB * NT * NH * sizeof(bf16);    // 2 MiB each
  const size_t off_k  = off_q + sz_qkv;
  const size_t off_vt = off_k + sz_qkv;

  bf16* Wt  = (bf16*)(ws + off_wt);
  bf16* Qw  = (bf16*)(ws + off_q);
  bf16* Kw  = (bf16*)(ws + off_k);
  bf16* Vtw = (bf16*)(ws + off_vt);

  hipLaunchKernelGGL(k_wt, dim3((3 * NH * NE + 255) / 256), dim3(256), 0, stream,
                     Wk, Wq, Wv, Wt);
  hipLaunchKernelGGL(k_proj, dim3(256, 3), dim3(256), 0, stream,
                     x, Wt, Qw, Kw, Vtw);
  hipLaunchKernelGGL(k_attn, dim3(1024), dim3(64), 0, stream,
                     Qw, Kw, Vtw, out);
}

// Round 2
// 289.935 us; speedup vs baseline: 1.0014x; 1.0014x over previous
//
#include <hip/hip_runtime.h>
#include <hip/hip_bf16.h>

#define NB 4
#define NT 4096
#define NE 768
#define NH 64
#define NS 256           // q-stripes per batch (16 rows each)

using bf16 = __hip_bfloat16;
typedef __attribute__((ext_vector_type(8))) short bf16x8;
typedef __attribute__((ext_vector_type(4))) float f32x4;

__device__ inline short f2bfs(float f) {
  bf16 h = __float2bfloat16(f);
  return __builtin_bit_cast(short, h);
}

// ---------------- kernel 0: W^T (bf16) precompute -------------------------
// Wt[m][h][e], m: 0=Wk, 1=Wq(×0.125 folded), 2=Wv
__global__ void k_wt(const float* __restrict__ Wk, const float* __restrict__ Wq,
                     const float* __restrict__ Wv, bf16* __restrict__ Wt) {
  int idx = blockIdx.x * 256 + threadIdx.x;
  if (idx >= 3 * NH * NE) return;
  int m = idx / (NH * NE);
  int r = idx - m * NH * NE;
  int h = r / NE;
  int e = r - h * NE;
  const float* W = (m == 0) ? Wk : ((m == 1) ? Wq : Wv);
  float v = W[e * NH + h];
  if (m == 1) v *= 0.125f;  // softmax scale folded into Q projection
  Wt[idx] = __float2bfloat16(v);
}

// ---------------- kernel 1: fused Q/K/V projections (MFMA) ----------------
// grid 256, block 256 (4 waves). Wave = 16-row stripe of x; computes all
// three projections from one x read / one bf16 conversion.
__global__ __launch_bounds__(256) void k_proj(const float* __restrict__ x,
                                              const bf16* __restrict__ Wt,
                                              bf16* __restrict__ Q,
                                              bf16* __restrict__ K,
                                              bf16* __restrict__ Vt) {
  const int wave = threadIdx.x >> 6;
  const int lane = threadIdx.x & 63;
  const int lr = lane & 15;   // A row / B col
  const int lk = lane >> 4;   // k sub-block
  const int stripe = blockIdx.x * 4 + wave;  // 0..1023
  const int row0 = stripe * 16;

  f32x4 acc[3][4];
#pragma unroll
  for (int m = 0; m < 3; ++m)
#pragma unroll
    for (int cb = 0; cb < 4; ++cb)
#pragma unroll
      for (int r = 0; r < 4; ++r) acc[m][cb][r] = 0.f;

  const float* xrow = x + (size_t)(row0 + lr) * NE;
#pragma unroll 2
  for (int ks = 0; ks < NE / 32; ++ks) {
    const int e0 = ks * 32 + lk * 8;
    float4 a0 = *reinterpret_cast<const float4*>(xrow + e0);
    float4 a1 = *reinterpret_cast<const float4*>(xrow + e0 + 4);
    bf16x8 af;
    af[0] = f2bfs(a0.x); af[1] = f2bfs(a0.y); af[2] = f2bfs(a0.z); af[3] = f2bfs(a0.w);
    af[4] = f2bfs(a1.x); af[5] = f2bfs(a1.y); af[6] = f2bfs(a1.z); af[7] = f2bfs(a1.w);
#pragma unroll
    for (int m = 0; m < 3; ++m)
#pragma unroll
      for (int cb = 0; cb < 4; ++cb) {
        bf16x8 bfr = *reinterpret_cast<const bf16x8*>(
            Wt + (size_t)m * NH * NE + (cb * 16 + lr) * NE + e0);
        acc[m][cb] = __builtin_amdgcn_mfma_f32_16x16x32_bf16(af, bfr, acc[m][cb], 0, 0, 0);
      }
  }

  const int trow = row0 + lk * 4;  // C/D: row=(lane>>4)*4+reg, col=lane&15
  // K
#pragma unroll
  for (int cb = 0; cb < 4; ++cb) {
    const int h = cb * 16 + lr;
#pragma unroll
    for (int r = 0; r < 4; ++r)
      K[(size_t)(trow + r) * NH + h] = __float2bfloat16(acc[0][cb][r]);
  }
  // Q (scale pre-folded)
#pragma unroll
  for (int cb = 0; cb < 4; ++cb) {
    const int h = cb * 16 + lr;
#pragma unroll
    for (int r = 0; r < 4; ++r)
      Q[(size_t)(trow + r) * NH + h] = __float2bfloat16(acc[1][cb][r]);
  }
  // V transposed: Vt[b][h][t]
  {
    const int b = trow >> 12;
    const int t = trow & (NT - 1);
#pragma unroll
    for (int cb = 0; cb < 4; ++cb) {
      const int h = cb * 16 + lr;
      ushort4 pk;
      pk.x = (unsigned short)f2bfs(acc[2][cb][0]);
      pk.y = (unsigned short)f2bfs(acc[2][cb][1]);
      pk.z = (unsigned short)f2bfs(acc[2][cb][2]);
      pk.w = (unsigned short)f2bfs(acc[2][cb][3]);
      *reinterpret_cast<ushort4*>(Vt + (size_t)(b * NH + h) * NT + t) = pk;
    }
  }
}

// ---------------- kernel 2a: split-KV causal flash attention (partials) ---
// grid NB*NS*MAXC single-wave blocks. Block -> (b, stripe s, chunk c).
// Chunk = up to CH KV-tiles of 64 keys. Writes partial (o,m,l) to ws.
__global__ __launch_bounds__(64) void k_attn_part(const bf16* __restrict__ Q,
                                                  const bf16* __restrict__ K,
                                                  const bf16* __restrict__ Vt,
                                                  float* __restrict__ part_o,
                                                  float* __restrict__ part_ml,
                                                  int CH, int MAXC) {
  __shared__ __align__(16) bf16 Pl[16][72];  // +8 pad: breaks bank aliasing
  const int lane = threadIdx.x;
  const int lr = lane & 15;
  const int lk = lane >> 4;
  const int gid = blockIdx.x;
  const int c = gid % MAXC;
  const int sr = (gid / MAXC) & (NS - 1);
  const int b = gid / (MAXC * NS);
  const int s = NS - 1 - sr;  // descending work size

  const int ntiles = (s >> 2) + 1;
  const int nchunks = (ntiles + CH - 1) / CH;
  if (c >= nchunks) return;
  const int kt0 = c * CH;
  const int kt1 = min(kt0 + CH, ntiles);
  const int qbase = s * 16;

  const bf16* Qb = Q + (size_t)(b * NT + qbase) * NH;
  const bf16* Kb = K + (size_t)b * NT * NH;
  const bf16* Vb = Vt + (size_t)b * NH * NT;

  bf16x8 qf[2];
#pragma unroll
  for (int ks = 0; ks < 2; ++ks)
    qf[ks] = *reinterpret_cast<const bf16x8*>(Qb + lr * NH + ks * 32 + lk * 8);

  f32x4 o[4];
#pragma unroll
  for (int cb = 0; cb < 4; ++cb)
#pragma unroll
    for (int r = 0; r < 4; ++r) o[cb][r] = 0.f;
  float mrow[4], lsum[4];
#pragma unroll
  for (int r = 0; r < 4; ++r) { mrow[r] = -1e30f; lsum[r] = 0.f; }

  for (int kt = kt0; kt < kt1; ++kt) {
    const int k0 = kt * 64;
    // ---- S = Q K^T over this 64-key tile
    f32x4 sa[4];
#pragma unroll
    for (int cb = 0; cb < 4; ++cb)
#pragma unroll
      for (int r = 0; r < 4; ++r) sa[cb][r] = 0.f;
#pragma unroll
    for (int ks = 0; ks < 2; ++ks)
#pragma unroll
      for (int cb = 0; cb < 4; ++cb) {
        bf16x8 kf = *reinterpret_cast<const bf16x8*>(
            Kb + (size_t)(k0 + cb * 16 + lr) * NH + ks * 32 + lk * 8);
        sa[cb] = __builtin_amdgcn_mfma_f32_16x16x32_bf16(qf[ks], kf, sa[cb], 0, 0, 0);
      }
    // ---- causal mask (diagonal tile only)
    if (kt == ntiles - 1) {
#pragma unroll
      for (int cb = 0; cb < 4; ++cb)
#pragma unroll
        for (int r = 0; r < 4; ++r) {
          const int kg = k0 + cb * 16 + lr;
          const int qg = qbase + lk * 4 + r;
          if (kg > qg) sa[cb][r] = -1e30f;
        }
    }
    // ---- online softmax (rows in 16-lane groups)
    float pm[4];
#pragma unroll
    for (int r = 0; r < 4; ++r)
      pm[r] = fmaxf(fmaxf(sa[0][r], sa[1][r]), fmaxf(sa[2][r], sa[3][r]));
#pragma unroll
    for (int msk = 1; msk < 16; msk <<= 1)
#pragma unroll
      for (int r = 0; r < 4; ++r)
        pm[r] = fmaxf(pm[r], __shfl_xor(pm[r], msk));
    float alpha[4], rs[4];
#pragma unroll
    for (int r = 0; r < 4; ++r) {
      const float mn = fmaxf(mrow[r], pm[r]);
      alpha[r] = __expf(mrow[r] - mn);
      mrow[r] = mn;
      rs[r] = 0.f;
    }
    __syncthreads();
#pragma unroll
    for (int cb = 0; cb < 4; ++cb)
#pragma unroll
      for (int r = 0; r < 4; ++r) {
        const float p = __expf(sa[cb][r] - mrow[r]);
        rs[r] += p;
        Pl[lk * 4 + r][cb * 16 + lr] = __float2bfloat16(p);
      }
#pragma unroll
    for (int msk = 1; msk < 16; msk <<= 1)
#pragma unroll
      for (int r = 0; r < 4; ++r) rs[r] += __shfl_xor(rs[r], msk);
#pragma unroll
    for (int r = 0; r < 4; ++r) lsum[r] = lsum[r] * alpha[r] + rs[r];
#pragma unroll
    for (int cb = 0; cb < 4; ++cb)
#pragma unroll
      for (int r = 0; r < 4; ++r) o[cb][r] *= alpha[r];
    __syncthreads();
    // ---- O += P V
    bf16x8 pa[2];
#pragma unroll
    for (int ks = 0; ks < 2; ++ks)
      pa[ks] = *reinterpret_cast<const bf16x8*>(&Pl[lr][ks * 32 + lk * 8]);
#pragma unroll
    for (int ks = 0; ks < 2; ++ks)
#pragma unroll
      for (int cb = 0; cb < 4; ++cb) {
        bf16x8 vf = *reinterpret_cast<const bf16x8*>(
            Vb + (size_t)(cb * 16 + lr) * NT + k0 + ks * 32 + lk * 8);
        o[cb] = __builtin_amdgcn_mfma_f32_16x16x32_bf16(pa[ks], vf, o[cb], 0, 0, 0);
      }
  }

  // ---- store partial (o rows×64 f32, then m[16], l[16])
  const size_t idx = ((size_t)(b * NS + s) * MAXC + c);
  float* po = part_o + idx * (16 * 64);
#pragma unroll
  for (int cb = 0; cb < 4; ++cb)
#pragma unroll
    for (int r = 0; r < 4; ++r)
      po[(lk * 4 + r) * 64 + cb * 16 + lr] = o[cb][r];
  if (lr == 0) {
    float* pml = part_ml + idx * 32;
#pragma unroll
    for (int r = 0; r < 4; ++r) {
      pml[lk * 4 + r] = mrow[r];
      pml[16 + lk * 4 + r] = lsum[r];
    }
  }
}

// ---------------- kernel 2b: combine partials + normalize -----------------
// grid NB*NS blocks × 64 threads; lane = output column.
__global__ __launch_bounds__(64) void k_attn_comb(const float* __restrict__ part_o,
                                                  const float* __restrict__ part_ml,
                                                  float* __restrict__ out,
                                                  int CH, int MAXC) {
  const int lane = threadIdx.x;
  const int gid = blockIdx.x;
  const int s = gid & (NS - 1);
  const int b = gid >> 8;
  const int ntiles = (s >> 2) + 1;
  const int nc = (ntiles + CH - 1) / CH;
  const size_t base = (size_t)(b * NS + s) * MAXC;
  float* ob = out + (size_t)(b * NT + s * 16) * NH;

  for (int r = 0; r < 16; ++r) {
    float M = -1e30f;
    for (int c = 0; c < nc; ++c)
      M = fmaxf(M, part_ml[(base + c) * 32 + r]);
    float L = 0.f, acc = 0.f;
    for (int c = 0; c < nc; ++c) {
      const float mc = part_ml[(base + c) * 32 + r];
      const float lc = part_ml[(base + c) * 32 + 16 + r];
      const float sc = __expf(mc - M);
      L += lc * sc;
      acc += part_o[(base + c) * (16 * 64) + r * 64 + lane] * sc;
    }
    ob[r * NH + lane] = acc / L;
  }
}

// ---------------- launcher ------------------------------------------------
extern "C" void kernel_launch(void* const* d_in, const int* in_sizes, int n_in,
                              void* d_out, int out_size, void* d_ws, size_t ws_size,
                              hipStream_t stream) {
  const float* x  = (const float*)d_in[0];
  const float* Wk = (const float*)d_in[1];
  const float* Wq = (const float*)d_in[2];
  const float* Wv = (const float*)d_in[3];
  float* out = (float*)d_out;

  char* ws = (char*)d_ws;
  const size_t sz_wt  = (size_t)3 * NH * NE * sizeof(bf16);
  const size_t sz_qkv = (size_t)NB * NT * NH * sizeof(bf16);
  const size_t off_wt = 0;
  const size_t off_q  = off_wt + ((sz_wt + 255) & ~size_t(255));
  const size_t off_k  = off_q + sz_qkv;
  const size_t off_vt = off_k + sz_qkv;
  const size_t off_pp = off_vt + sz_qkv;

  // pick split factor based on workspace
  int MAXC = 8, CH = 8;
  {
    const size_t need8 = off_pp +
        (size_t)NB * NS * 8 * (16 * 64 + 32) * sizeof(float);
    if (ws_size < need8) { MAXC = 1; CH = 64; }
  }
  const size_t n_part = (size_t)NB * NS * MAXC;
  const size_t off_po = off_pp;
  const size_t off_ml = off_po + n_part * 16 * 64 * sizeof(float);

  bf16* Wt  = (bf16*)(ws + off_wt);
  bf16* Qw  = (bf16*)(ws + off_q);
  bf16* Kw  = (bf16*)(ws + off_k);
  bf16* Vtw = (bf16*)(ws + off_vt);
  float* part_o  = (float*)(ws + off_po);
  float* part_ml = (float*)(ws + off_ml);

  hipLaunchKernelGGL(k_wt, dim3((3 * NH * NE + 255) / 256), dim3(256), 0, stream,
                     Wk, Wq, Wv, Wt);
  hipLaunchKernelGGL(k_proj, dim3(256), dim3(256), 0, stream,
                     x, Wt, Qw, Kw, Vtw);
  hipLaunchKernelGGL(k_attn_part, dim3(NB * NS * MAXC), dim3(64), 0, stream,
                     Qw, Kw, Vtw, part_o, part_ml, CH, MAXC);
  hipLaunchKernelGGL(k_attn_comb, dim3(NB * NS), dim3(64), 0, stream,
                     part_o, part_ml, out, CH, MAXC);
}

// Round 3
// 192.045 us; speedup vs baseline: 1.5118x; 1.5097x over previous
//
#include <hip/hip_runtime.h>
#include <hip/hip_bf16.h>

#define NB 4
#define NT 4096
#define NE 768
#define NH 64

using bf16 = __hip_bfloat16;
typedef __attribute__((ext_vector_type(8))) short bf16x8;
typedef __attribute__((ext_vector_type(4))) float f32x4;

__device__ inline short f2bfs(float f) {
  bf16 h = __float2bfloat16(f);
  return __builtin_bit_cast(short, h);
}

// async global->LDS, 16B per lane; LDS dest = uniform base + lane*16
#define GLOAD_LDS16(gsrc, ldst)                                        \
  __builtin_amdgcn_global_load_lds(                                    \
      (const __attribute__((address_space(1))) void*)(gsrc),           \
      (__attribute__((address_space(3))) void*)(ldst), 16, 0, 0)

// ---------------- kernel 0: W^T (bf16) precompute -------------------------
__global__ void k_wt(const float* __restrict__ Wk, const float* __restrict__ Wq,
                     const float* __restrict__ Wv, bf16* __restrict__ Wt) {
  int idx = blockIdx.x * 256 + threadIdx.x;
  if (idx >= 3 * NH * NE) return;
  int m = idx / (NH * NE);
  int r = idx - m * NH * NE;
  int h = r / NE;
  int e = r - h * NE;
  const float* W = (m == 0) ? Wk : ((m == 1) ? Wq : Wv);
  float v = W[e * NH + h];
  if (m == 1) v *= 0.125f;  // softmax scale folded into Q
  Wt[idx] = __float2bfloat16(v);
}

// ---------------- kernel 1: fused Q/K/V projections -----------------------
// 512 blocks x 256 thr. Block stages 32 x-rows to LDS (bf16, XOR-swizzled),
// wave (sr,half) computes 16 rows x 96 cols of the fused [192]-col output.
__global__ __launch_bounds__(256) void k_proj(const float* __restrict__ x,
                                              const bf16* __restrict__ Wt,
                                              bf16* __restrict__ Q,
                                              bf16* __restrict__ K,
                                              bf16* __restrict__ Vt) {
  __shared__ __align__(16) bf16 xl[32][768];  // 48 KB
  const int tid = threadIdx.x;
  const int wave = tid >> 6, lane = tid & 63;
  const int lr = lane & 15, lk = lane >> 4;
  const int row0blk = blockIdx.x * 32;

  // stage x: 32x768 f32 -> bf16 LDS, chunk^row&7 swizzle on 16B chunks
#pragma unroll
  for (int j = 0; j < 12; ++j) {
    const int e = (j * 256 + tid) * 8;
    const int row = e / 768;
    const int col = e - row * 768;
    const int chunk = col >> 3;
    const int sch = (chunk & ~7) | ((chunk ^ row) & 7);
    const float* xp = x + (size_t)(row0blk + row) * NE + col;
    float4 a0 = *reinterpret_cast<const float4*>(xp);
    float4 a1 = *reinterpret_cast<const float4*>(xp + 4);
    bf16x8 af;
    af[0] = f2bfs(a0.x); af[1] = f2bfs(a0.y); af[2] = f2bfs(a0.z); af[3] = f2bfs(a0.w);
    af[4] = f2bfs(a1.x); af[5] = f2bfs(a1.y); af[6] = f2bfs(a1.z); af[7] = f2bfs(a1.w);
    *reinterpret_cast<bf16x8*>((char*)xl + row * 1536 + sch * 16) = af;
  }
  __syncthreads();

  const int sr = wave >> 1, half = wave & 1;
  const int rbase = sr * 16;
  f32x4 acc[6];
#pragma unroll
  for (int cb = 0; cb < 6; ++cb)
#pragma unroll
    for (int r = 0; r < 4; ++r) acc[cb][r] = 0.f;

#pragma unroll 4
  for (int ks = 0; ks < NE / 32; ++ks) {
    const int chunk = ks * 4 + lk;
    const int arow = rbase + lr;
    const int sch = (chunk & ~7) | ((chunk ^ arow) & 7);
    bf16x8 af = *reinterpret_cast<const bf16x8*>((const char*)xl + arow * 1536 + sch * 16);
    const int e0 = ks * 32 + lk * 8;
#pragma unroll
    for (int cb = 0; cb < 6; ++cb) {
      const int hh = half * 96 + cb * 16 + lr;
      bf16x8 bfr = *reinterpret_cast<const bf16x8*>(Wt + (size_t)hh * NE + e0);
      acc[cb] = __builtin_amdgcn_mfma_f32_16x16x32_bf16(af, bfr, acc[cb], 0, 0, 0);
    }
  }

  const int trow = row0blk + rbase + lk * 4;  // C/D: row=(lane>>4)*4+reg
#pragma unroll
  for (int cb = 0; cb < 6; ++cb) {
    const int hh0 = half * 96 + cb * 16;
    const int m = hh0 >> 6;
    const int h = (hh0 & 63) + lr;
    if (m == 0) {
#pragma unroll
      for (int r = 0; r < 4; ++r)
        K[(size_t)(trow + r) * NH + h] = __float2bfloat16(acc[cb][r]);
    } else if (m == 1) {
#pragma unroll
      for (int r = 0; r < 4; ++r)
        Q[(size_t)(trow + r) * NH + h] = __float2bfloat16(acc[cb][r]);
    } else {
      const int bb = trow >> 12;
      const int t = trow & (NT - 1);
      ushort4 pk;
      pk.x = (unsigned short)f2bfs(acc[cb][0]);
      pk.y = (unsigned short)f2bfs(acc[cb][1]);
      pk.z = (unsigned short)f2bfs(acc[cb][2]);
      pk.w = (unsigned short)f2bfs(acc[cb][3]);
      *reinterpret_cast<ushort4*>(Vt + (size_t)(bb * NH + h) * NT + t) = pk;
    }
  }
}

// ---------------- kernel 2a: split-KV flash attention (partials) ----------
// Block = 4 waves, 64-row Q-tile. K/V 64-key tiles staged to LDS via
// global_load_lds (double-buffered, prefetch in flight during compute).
__global__ __launch_bounds__(256) void k_attn_part(const bf16* __restrict__ Q,
                                                   const bf16* __restrict__ K,
                                                   const bf16* __restrict__ Vt,
                                                   float* __restrict__ part_o,
                                                   float* __restrict__ part_ml,
                                                   int CH, int MAXC) {
  __shared__ __align__(16) bf16 Kl[2][64][64];  // 16 KB
  __shared__ __align__(16) bf16 Vl[2][64][64];  // 16 KB
  __shared__ __align__(16) bf16 Pl[4][16][72];  // 9 KB, per-wave P
  const int tid = threadIdx.x;
  const int wave = tid >> 6, lane = tid & 63;
  const int lr = lane & 15, lk = lane >> 4;
  const int gid = blockIdx.x;
  const int c = gid % MAXC;
  const int sr = (gid / MAXC) & 63;
  const int b = gid / (MAXC * 64);
  const int s = 63 - sr;  // descending work: big stripes dispatched first
  const int ntiles = s + 1;
  const int nchunks = (ntiles + CH - 1) / CH;
  if (c >= nchunks) return;
  const int kt0 = c * CH;
  const int kt1 = min(kt0 + CH, ntiles);
  const int qw = s * 64 + wave * 16;

  const bf16* Qb = Q + (size_t)(b * NT + qw) * NH;
  const bf16* Kb = K + (size_t)b * NT * NH;
  const bf16* Vb = Vt + (size_t)b * NH * NT;

  bf16x8 qf[2];
#pragma unroll
  for (int ks = 0; ks < 2; ++ks)
    qf[ks] = *reinterpret_cast<const bf16x8*>(Qb + lr * NH + ks * 32 + lk * 8);

  f32x4 o[4];
#pragma unroll
  for (int cb = 0; cb < 4; ++cb)
#pragma unroll
    for (int r = 0; r < 4; ++r) o[cb][r] = 0.f;
  float mrow[4], lsum[4];
#pragma unroll
  for (int r = 0; r < 4; ++r) { mrow[r] = -1e30f; lsum[r] = 0.f; }

  const int rsub = lane >> 3, ch = lane & 7;
  // stage first tile into buf 0 (per-lane source pre-swizzled: rule 21)
#pragma unroll
  for (int j = 0; j < 2; ++j) {
    const int row = wave * 16 + j * 8 + rsub;
    const int sch = ch ^ (row & 7);
    GLOAD_LDS16(Kb + (size_t)(kt0 * 64 + row) * NH + sch * 8, &Kl[0][wave * 16 + j * 8][0]);
    GLOAD_LDS16(Vb + (size_t)row * NT + kt0 * 64 + sch * 8, &Vl[0][wave * 16 + j * 8][0]);
  }

  for (int kt = kt0; kt < kt1; ++kt) {
    const int buf = (kt - kt0) & 1;
    __syncthreads();  // drains vmcnt: buf staged; buf^1 free to overwrite
    if (kt + 1 < kt1) {
      const int nk0 = (kt + 1) * 64;
#pragma unroll
      for (int j = 0; j < 2; ++j) {
        const int row = wave * 16 + j * 8 + rsub;
        const int sch = ch ^ (row & 7);
        GLOAD_LDS16(Kb + (size_t)(nk0 + row) * NH + sch * 8, &Kl[buf ^ 1][wave * 16 + j * 8][0]);
        GLOAD_LDS16(Vb + (size_t)row * NT + nk0 + sch * 8, &Vl[buf ^ 1][wave * 16 + j * 8][0]);
      }
    }
    const int k0 = kt * 64;
    const char* Kbase = (const char*)&Kl[buf][0][0];
    const char* Vbase = (const char*)&Vl[buf][0][0];

    // ---- S = Q K^T
    f32x4 sa[4];
#pragma unroll
    for (int cb = 0; cb < 4; ++cb)
#pragma unroll
      for (int r = 0; r < 4; ++r) sa[cb][r] = 0.f;
#pragma unroll
    for (int ks = 0; ks < 2; ++ks)
#pragma unroll
      for (int cb = 0; cb < 4; ++cb) {
        const int row = cb * 16 + lr;
        bf16x8 kf = *reinterpret_cast<const bf16x8*>(
            Kbase + row * 128 + (((ks * 4 + lk) ^ (row & 7)) << 4));
        sa[cb] = __builtin_amdgcn_mfma_f32_16x16x32_bf16(qf[ks], kf, sa[cb], 0, 0, 0);
      }
    // ---- causal mask (diagonal tile only)
    if (kt == s) {
#pragma unroll
      for (int cb = 0; cb < 4; ++cb)
#pragma unroll
        for (int r = 0; r < 4; ++r) {
          const int kg = k0 + cb * 16 + lr;
          const int qg = qw + lk * 4 + r;
          if (kg > qg) sa[cb][r] = -1e30f;
        }
    }
    // ---- online softmax (rows in 16-lane groups)
    float pm[4];
#pragma unroll
    for (int r = 0; r < 4; ++r)
      pm[r] = fmaxf(fmaxf(sa[0][r], sa[1][r]), fmaxf(sa[2][r], sa[3][r]));
#pragma unroll
    for (int msk = 1; msk < 16; msk <<= 1)
#pragma unroll
      for (int r = 0; r < 4; ++r)
        pm[r] = fmaxf(pm[r], __shfl_xor(pm[r], msk));
    float alpha[4], rs[4];
#pragma unroll
    for (int r = 0; r < 4; ++r) {
      const float mn = fmaxf(mrow[r], pm[r]);
      alpha[r] = __expf(mrow[r] - mn);
      mrow[r] = mn;
      rs[r] = 0.f;
    }
#pragma unroll
    for (int cb = 0; cb < 4; ++cb)
#pragma unroll
      for (int r = 0; r < 4; ++r) {
        const float p = __expf(sa[cb][r] - mrow[r]);
        rs[r] += p;
        Pl[wave][lk * 4 + r][cb * 16 + lr] = __float2bfloat16(p);
      }
#pragma unroll
    for (int msk = 1; msk < 16; msk <<= 1)
#pragma unroll
      for (int r = 0; r < 4; ++r) rs[r] += __shfl_xor(rs[r], msk);
#pragma unroll
    for (int r = 0; r < 4; ++r) lsum[r] = lsum[r] * alpha[r] + rs[r];
#pragma unroll
    for (int cb = 0; cb < 4; ++cb)
#pragma unroll
      for (int r = 0; r < 4; ++r) o[cb][r] *= alpha[r];
    // ---- O += P V
    bf16x8 pa[2];
#pragma unroll
    for (int ks = 0; ks < 2; ++ks)
      pa[ks] = *reinterpret_cast<const bf16x8*>(&Pl[wave][lr][ks * 32 + lk * 8]);
#pragma unroll
    for (int ks = 0; ks < 2; ++ks)
#pragma unroll
      for (int cb = 0; cb < 4; ++cb) {
        const int row = cb * 16 + lr;
        bf16x8 vf = *reinterpret_cast<const bf16x8*>(
            Vbase + row * 128 + (((ks * 4 + lk) ^ (row & 7)) << 4));
        o[cb] = __builtin_amdgcn_mfma_f32_16x16x32_bf16(pa[ks], vf, o[cb], 0, 0, 0);
      }
  }

  // ---- store partials: o [64][64] f32, ml [2][64]
  const size_t idx = (size_t)(b * 64 + s) * MAXC + c;
  float* po = part_o + idx * 4096;
#pragma unroll
  for (int cb = 0; cb < 4; ++cb)
#pragma unroll
    for (int r = 0; r < 4; ++r)
      po[(wave * 16 + lk * 4 + r) * 64 + cb * 16 + lr] = o[cb][r];
  if (lr == 0) {
    float* pml = part_ml + idx * 128;
#pragma unroll
    for (int r = 0; r < 4; ++r) {
      pml[wave * 16 + lk * 4 + r] = mrow[r];
      pml[64 + wave * 16 + lk * 4 + r] = lsum[r];
    }
  }
}

// ---------------- kernel 2b: combine + normalize --------------------------
// grid NB*64, 256 thr; thread -> (row = tid>>2, 16 cols = (tid&3)*16..)
__global__ __launch_bounds__(256) void k_attn_comb(const float* __restrict__ part_o,
                                                   const float* __restrict__ part_ml,
                                                   float* __restrict__ out,
                                                   int CH, int MAXC) {
  const int gid = blockIdx.x;
  const int s = gid & 63;
  const int b = gid >> 6;
  const int row = threadIdx.x >> 2;
  const int cq = threadIdx.x & 3;
  const int nc = (s + CH) / CH;
  const size_t base = (size_t)(b * 64 + s) * MAXC;

  float M = -1e30f;
  for (int c = 0; c < nc; ++c)
    M = fmaxf(M, part_ml[(base + c) * 128 + row]);
  float L = 0.f;
  float4 a0 = {0, 0, 0, 0}, a1 = {0, 0, 0, 0}, a2 = {0, 0, 0, 0}, a3 = {0, 0, 0, 0};
  for (int c = 0; c < nc; ++c) {
    const float mc = part_ml[(base + c) * 128 + row];
    const float lc = part_ml[(base + c) * 128 + 64 + row];
    const float sc = __expf(mc - M);
    L += lc * sc;
    const float4* op = reinterpret_cast<const float4*>(
        part_o + (base + c) * 4096 + row * 64 + cq * 16);
    float4 v0 = op[0], v1 = op[1], v2 = op[2], v3 = op[3];
    a0.x += v0.x * sc; a0.y += v0.y * sc; a0.z += v0.z * sc; a0.w += v0.w * sc;
    a1.x += v1.x * sc; a1.y += v1.y * sc; a1.z += v1.z * sc; a1.w += v1.w * sc;
    a2.x += v2.x * sc; a2.y += v2.y * sc; a2.z += v2.z * sc; a2.w += v2.w * sc;
    a3.x += v3.x * sc; a3.y += v3.y * sc; a3.z += v3.z * sc; a3.w += v3.w * sc;
  }
  const float inv = 1.f / L;
  float4* outp = reinterpret_cast<float4*>(
      out + (size_t)(b * NT + s * 64 + row) * NH + cq * 16);
  a0.x *= inv; a0.y *= inv; a0.z *= inv; a0.w *= inv;
  a1.x *= inv; a1.y *= inv; a1.z *= inv; a1.w *= inv;
  a2.x *= inv; a2.y *= inv; a2.z *= inv; a2.w *= inv;
  a3.x *= inv; a3.y *= inv; a3.z *= inv; a3.w *= inv;
  outp[0] = a0; outp[1] = a1; outp[2] = a2; outp[3] = a3;
}

// ---------------- launcher ------------------------------------------------
extern "C" void kernel_launch(void* const* d_in, const int* in_sizes, int n_in,
                              void* d_out, int out_size, void* d_ws, size_t ws_size,
                              hipStream_t stream) {
  const float* x  = (const float*)d_in[0];
  const float* Wk = (const float*)d_in[1];
  const float* Wq = (const float*)d_in[2];
  const float* Wv = (const float*)d_in[3];
  float* out = (float*)d_out;

  char* ws = (char*)d_ws;
  const size_t sz_wt  = (size_t)3 * NH * NE * sizeof(bf16);
  const size_t sz_qkv = (size_t)NB * NT * NH * sizeof(bf16);
  const size_t off_q  = (sz_wt + 255) & ~size_t(255);
  const size_t off_k  = off_q + sz_qkv;
  const size_t off_vt = off_k + sz_qkv;
  const size_t off_pp = off_vt + sz_qkv;

  int MAXC = 4, CH = 16;
  {
    const size_t need = off_pp +
        (size_t)NB * 64 * 4 * (4096 + 128) * sizeof(float);
    if (ws_size < need) { MAXC = 1; CH = 64; }
  }
  const size_t n_idx = (size_t)NB * 64 * MAXC;
  const size_t off_po = off_pp;
  const size_t off_ml = off_po + n_idx * 4096 * sizeof(float);

  bf16* Wt  = (bf16*)(ws);
  bf16* Qw  = (bf16*)(ws + off_q);
  bf16* Kw  = (bf16*)(ws + off_k);
  bf16* Vtw = (bf16*)(ws + off_vt);
  float* part_o  = (float*)(ws + off_po);
  float* part_ml = (float*)(ws + off_ml);

  hipLaunchKernelGGL(k_wt, dim3((3 * NH * NE + 255) / 256), dim3(256), 0, stream,
                     Wk, Wq, Wv, Wt);
  hipLaunchKernelGGL(k_proj, dim3(NB * NT / 32), dim3(256), 0, stream,
                     x, Wt, Qw, Kw, Vtw);
  hipLaunchKernelGGL(k_attn_part, dim3(NB * 64 * MAXC), dim3(256), 0, stream,
                     Qw, Kw, Vtw, part_o, part_ml, CH, MAXC);
  hipLaunchKernelGGL(k_attn_comb, dim3(NB * 64), dim3(256), 0, stream,
                     part_o, part_ml, out, CH, MAXC);
}

// Round 4
// 157.307 us; speedup vs baseline: 1.8456x; 1.2208x over previous
//
#include <hip/hip_runtime.h>
#include <hip/hip_bf16.h>

#define NB 4
#define NT 4096
#define NE 768
#define NH 64

using bf16 = __hip_bfloat16;
typedef __attribute__((ext_vector_type(8))) short bf16x8;
typedef __attribute__((ext_vector_type(4))) float f32x4;
typedef __attribute__((ext_vector_type(16))) float f32x16;
typedef __attribute__((ext_vector_type(4))) unsigned int u32x4;

// softmax scale 1/8 with log2(e) folded -> use exp2 everywhere
#define QSCALE 0.18033688011112042f  /* 0.125 * log2(e) */

__device__ inline short f2bfs(float f) {
  bf16 h = __float2bfloat16(f);
  return __builtin_bit_cast(short, h);
}
__device__ inline unsigned pack_bf2(float a, float b) {
  unsigned short ua = __builtin_bit_cast(unsigned short, __float2bfloat16(a));
  unsigned short ub = __builtin_bit_cast(unsigned short, __float2bfloat16(b));
  return ((unsigned)ub << 16) | ua;
}

#define GLOAD_LDS16(gsrc, ldst)                                        \
  __builtin_amdgcn_global_load_lds(                                    \
      (const __attribute__((address_space(1))) void*)(gsrc),           \
      (__attribute__((address_space(3))) void*)(ldst), 16, 0, 0)

// ---------------- kernel 0: W -> Wt2 fragment layout ----------------------
// Wt2[cbg][ks][lane][8]: cbg = m*4+cl (16-col block), ks = 24 k-steps,
// element j = W[e = ks*32 + (lane>>4)*8 + j][h = (cbg&3)*16 + (lane&15)].
// grid 3*24 blocks x 256 thr: block (m, ks); coalesced read + LDS transpose.
__global__ __launch_bounds__(256) void k_wt(const float* __restrict__ Wk,
                                            const float* __restrict__ Wq,
                                            const float* __restrict__ Wv,
                                            bf16* __restrict__ Wt2) {
  __shared__ float xl[32][65];
  const int m = blockIdx.x / 24;
  const int ks = blockIdx.x % 24;
  const int tid = threadIdx.x;
  const float* W = (m == 0) ? Wk : ((m == 1) ? Wq : Wv);
  const float scale = (m == 1) ? QSCALE : 1.0f;
  const int e0 = ks * 32;
#pragma unroll
  for (int i = 0; i < 8; ++i) {
    const int lin = i * 256 + tid;
    xl[lin >> 6][lin & 63] = W[(size_t)(e0 + (lin >> 6)) * NH + (lin & 63)];
  }
  __syncthreads();
  const int lane = tid & 63, w = tid >> 6;
  const int cbg = m * 4 + w;
  bf16x8 t;
#pragma unroll
  for (int j = 0; j < 8; ++j)
    t[j] = f2bfs(xl[((lane >> 4) << 3) + j][w * 16 + (lane & 15)] * scale);
  *reinterpret_cast<bf16x8*>(Wt2 + (((size_t)cbg * 24 + ks) * 64 + lane) * 8) = t;
}

// ---------------- kernel 1: fused Q/K/V projections -----------------------
// 1024 blocks x 256 thr; block = 16-row x-stripe staged in LDS (swizzled);
// wave w computes cols cbg = w*3 .. w*3+2 (48 of 192). B coalesced via Wt2.
__global__ __launch_bounds__(256) void k_proj(const float* __restrict__ x,
                                              const bf16* __restrict__ Wt2,
                                              bf16* __restrict__ Q,
                                              bf16* __restrict__ K,
                                              bf16* __restrict__ Vt) {
  __shared__ __align__(16) bf16 xl[16][768];  // 24 KB
  const int tid = threadIdx.x;
  const int wave = tid >> 6, lane = tid & 63;
  const int lr = lane & 15, lk = lane >> 4;
  const int row0 = blockIdx.x * 16;

#pragma unroll
  for (int j = 0; j < 6; ++j) {
    const int e = (j * 256 + tid) * 8;
    const int row = e / 768;
    const int col = e - row * 768;
    const int chunk = col >> 3;
    const int sch = (chunk & ~7) | ((chunk ^ row) & 7);
    const float* xp = x + (size_t)(row0 + row) * NE + col;
    float4 a0 = *reinterpret_cast<const float4*>(xp);
    float4 a1 = *reinterpret_cast<const float4*>(xp + 4);
    bf16x8 af;
    af[0] = f2bfs(a0.x); af[1] = f2bfs(a0.y); af[2] = f2bfs(a0.z); af[3] = f2bfs(a0.w);
    af[4] = f2bfs(a1.x); af[5] = f2bfs(a1.y); af[6] = f2bfs(a1.z); af[7] = f2bfs(a1.w);
    *reinterpret_cast<bf16x8*>((char*)xl + row * 1536 + sch * 16) = af;
  }
  __syncthreads();

  f32x4 acc[3];
#pragma unroll
  for (int cb = 0; cb < 3; ++cb)
#pragma unroll
    for (int r = 0; r < 4; ++r) acc[cb][r] = 0.f;

#pragma unroll 4
  for (int ks = 0; ks < 24; ++ks) {
    const int chunk = ks * 4 + lk;
    const int sch = (chunk & ~7) | ((chunk ^ lr) & 7);
    bf16x8 af = *reinterpret_cast<const bf16x8*>((const char*)xl + lr * 1536 + sch * 16);
#pragma unroll
    for (int cb = 0; cb < 3; ++cb) {
      bf16x8 bfr = *reinterpret_cast<const bf16x8*>(
          Wt2 + (((size_t)(wave * 3 + cb) * 24 + ks) * 64 + lane) * 8);
      acc[cb] = __builtin_amdgcn_mfma_f32_16x16x32_bf16(af, bfr, acc[cb], 0, 0, 0);
    }
  }

  const int trow = row0 + lk * 4;
#pragma unroll
  for (int cb = 0; cb < 3; ++cb) {
    const int hh0 = (wave * 3 + cb) * 16;
    const int m = hh0 >> 6;
    const int h = (hh0 & 63) + lr;
    if (m == 0) {
#pragma unroll
      for (int r = 0; r < 4; ++r)
        K[(size_t)(trow + r) * NH + h] = __float2bfloat16(acc[cb][r]);
    } else if (m == 1) {
#pragma unroll
      for (int r = 0; r < 4; ++r)
        Q[(size_t)(trow + r) * NH + h] = __float2bfloat16(acc[cb][r]);
    } else {
      const int bb = trow >> 12;
      const int t = trow & (NT - 1);
      ushort4 pk;
      pk.x = (unsigned short)f2bfs(acc[cb][0]);
      pk.y = (unsigned short)f2bfs(acc[cb][1]);
      pk.z = (unsigned short)f2bfs(acc[cb][2]);
      pk.w = (unsigned short)f2bfs(acc[cb][3]);
      *reinterpret_cast<ushort4*>(Vt + (size_t)(bb * NH + h) * NT + t) = pk;
    }
  }
}

// ---------------- kernel 2a: split-KV flash attention ---------------------
// Block = 4 waves x 32 q-rows (interleaved) = 128-row stripe; 64-key tiles
// double-buffered in LDS. 32x32x16 MFMA, swapped QK^T (D[key][q]) -> in-lane
// softmax; P kept in registers (bf16 pairs + shfl_xor(32) redistribution).
__device__ inline void stage_kv(const bf16* Kb, const bf16* Vb, int k0,
                                bf16* Kl, bf16* Vl, int wave, int lane) {
  const int rsub = lane >> 3, ch = lane & 7;
#pragma unroll
  for (int j = 0; j < 2; ++j) {
    const int br = j * 32 + wave * 8;
    const int row = br + rsub;
    const int sch = ch ^ (row & 7);
    GLOAD_LDS16(Kb + (size_t)(k0 + row) * NH + sch * 8, Kl + br * 64);
    GLOAD_LDS16(Vb + (size_t)row * NT + k0 + sch * 8, Vl + br * 64);
  }
}

__global__ __launch_bounds__(256) void k_attn_part(const bf16* __restrict__ Q,
                                                   const bf16* __restrict__ K,
                                                   const bf16* __restrict__ Vt,
                                                   float* __restrict__ part_o,
                                                   float* __restrict__ part_ml,
                                                   int CH, int MAXC) {
  __shared__ __align__(16) bf16 Kl[2][64][64];  // 16 KB
  __shared__ __align__(16) bf16 Vl[2][64][64];  // 16 KB
  const int tid = threadIdx.x;
  const int wave = tid >> 6, lane = tid & 63;
  const int l31 = lane & 31, hi5 = lane >> 5;
  const int gid = blockIdx.x;
  const int c = gid % MAXC;
  const int srs = (gid / MAXC) & 31;
  const int b = gid / (MAXC * 32);
  const int s = 31 - srs;                       // big stripes first
  const int ntiles = 2 * s + 2;
  const int nch = (ntiles + CH - 1) / CH;
  if (c >= nch) return;
  const int kt0 = c * CH;
  const int kt1 = min(kt0 + CH, ntiles);
  const int qblk = s * 128;
  // interleaved q so all waves share the same causal diagonal profile
  const int qrow = 8 * wave + (l31 & 7) + 32 * (l31 >> 3);  // 0..127
  const int qcol = qblk + qrow;

  const bf16* Qb = Q + (size_t)(b * NT + qcol) * NH;
  const bf16* Kb = K + (size_t)b * NT * NH;
  const bf16* Vb = Vt + (size_t)b * NH * NT;

  bf16x8 qf[4];
#pragma unroll
  for (int ks = 0; ks < 4; ++ks)
    qf[ks] = *reinterpret_cast<const bf16x8*>(Qb + ks * 16 + hi5 * 8);

  f32x16 o[2];
#pragma unroll
  for (int hb = 0; hb < 2; ++hb)
#pragma unroll
    for (int r = 0; r < 16; ++r) o[hb][r] = 0.f;
  float m = -1e30f, lsum = 0.f;

  stage_kv(Kb, Vb, kt0 * 64, &Kl[0][0][0], &Vl[0][0][0], wave, lane);

  for (int kt = kt0; kt < kt1; ++kt) {
    const int buf = (kt - kt0) & 1;
    __syncthreads();  // drains staging vmcnt; buf ready, buf^1 reusable
    if (kt + 1 < kt1)
      stage_kv(Kb, Vb, (kt + 1) * 64, &Kl[buf ^ 1][0][0], &Vl[buf ^ 1][0][0], wave, lane);
    const int k0 = kt * 64;
    const bf16* Klb = &Kl[buf][0][0];
    const bf16* Vlb = &Vl[buf][0][0];

    // ---- S^T = K Q^T (D[key][q]): A = K rows, B = Q cols
    f32x16 sa[2];
#pragma unroll
    for (int kb = 0; kb < 2; ++kb) {
#pragma unroll
      for (int r = 0; r < 16; ++r) sa[kb][r] = 0.f;
      __builtin_amdgcn_s_setprio(1);
#pragma unroll
      for (int ks = 0; ks < 4; ++ks) {
        const int row = l31 + 32 * kb;
        const int sch = (hi5 + 2 * ks) ^ (row & 7);
        bf16x8 kf = *reinterpret_cast<const bf16x8*>(Klb + row * 64 + sch * 8);
        sa[kb] = __builtin_amdgcn_mfma_f32_32x32x16_bf16(kf, qf[ks], sa[kb], 0, 0, 0);
      }
      __builtin_amdgcn_s_setprio(0);
    }
    // ---- causal mask (only last two tiles of the stripe touch diagonal)
    if (kt >= 2 * s) {
#pragma unroll
      for (int kb = 0; kb < 2; ++kb)
#pragma unroll
        for (int r = 0; r < 16; ++r) {
          const int kg = k0 + (r & 3) + 8 * (r >> 2) + 4 * hi5 + 32 * kb;
          if (kg > qcol) sa[kb][r] = -1e30f;
        }
    }
    // ---- in-lane softmax for query qcol (keys split across lane, lane^32)
    float pm = sa[0][0];
#pragma unroll
    for (int r = 1; r < 16; ++r) pm = fmaxf(pm, sa[0][r]);
#pragma unroll
    for (int r = 0; r < 16; ++r) pm = fmaxf(pm, sa[1][r]);
    pm = fmaxf(pm, __shfl_xor(pm, 32));
    if (!__all(pm - m <= 6.f)) {  // defer-max: skip rescale when max stable
      const float mn = fmaxf(m, pm);
      const float alpha = exp2f(m - mn);
      lsum *= alpha;
#pragma unroll
      for (int hb = 0; hb < 2; ++hb)
#pragma unroll
        for (int r = 0; r < 16; ++r) o[hb][r] *= alpha;
      m = mn;
    }
    float rs = 0.f;
#pragma unroll
    for (int kb = 0; kb < 2; ++kb)
#pragma unroll
      for (int r = 0; r < 16; ++r) {
        const float p = exp2f(sa[kb][r] - m);
        sa[kb][r] = p;
        rs += p;
      }
    rs += __shfl_xor(rs, 32);
    lsum += rs;
    // ---- pack P to bf16 pairs; redistribute halves via shfl_xor(32)
    unsigned pk[2][4][2];
#pragma unroll
    for (int kb = 0; kb < 2; ++kb)
#pragma unroll
      for (int q4 = 0; q4 < 4; ++q4)
#pragma unroll
        for (int p = 0; p < 2; ++p)
          pk[kb][q4][p] = pack_bf2(sa[kb][4 * q4 + 2 * p], sa[kb][4 * q4 + 2 * p + 1]);
    // ---- O^T += V^T P^T: A = V^T rows (h), B = P cols (q)
#pragma unroll
    for (int kb16 = 0; kb16 < 4; ++kb16) {
      const int kb32 = kb16 >> 1;
      const int q4a = 2 * (kb16 & 1);
      const unsigned X0 = pk[kb32][q4a][0], X1 = pk[kb32][q4a][1];
      const unsigned Y0 = pk[kb32][q4a + 1][0], Y1 = pk[kb32][q4a + 1][1];
      const unsigned pX0 = __shfl_xor((int)X0, 32), pX1 = __shfl_xor((int)X1, 32);
      const unsigned pY0 = __shfl_xor((int)Y0, 32), pY1 = __shfl_xor((int)Y1, 32);
      u32x4 pw;
      pw[0] = hi5 ? pY0 : X0;
      pw[1] = hi5 ? pY1 : X1;
      pw[2] = hi5 ? Y0 : pX0;
      pw[3] = hi5 ? Y1 : pX1;
      const bf16x8 pf = __builtin_bit_cast(bf16x8, pw);
      __builtin_amdgcn_s_setprio(1);
#pragma unroll
      for (int hb = 0; hb < 2; ++hb) {
        const int row = l31 + 32 * hb;
        const int sch = (hi5 + 2 * kb16) ^ (row & 7);
        bf16x8 vf = *reinterpret_cast<const bf16x8*>(Vlb + row * 64 + sch * 8);
        o[hb] = __builtin_amdgcn_mfma_f32_32x32x16_bf16(vf, pf, o[hb], 0, 0, 0);
      }
      __builtin_amdgcn_s_setprio(0);
    }
  }

  // ---- store partials: po[128 q][64 h], pml[2][128]
  const size_t idx = (size_t)(b * 32 + s) * MAXC + c;
  float* po = part_o + idx * (128 * 64);
#pragma unroll
  for (int hb = 0; hb < 2; ++hb)
#pragma unroll
    for (int q4 = 0; q4 < 4; ++q4) {
      const int h0 = 32 * hb + 8 * q4 + 4 * hi5;
      float4 v;
      v.x = o[hb][4 * q4 + 0];
      v.y = o[hb][4 * q4 + 1];
      v.z = o[hb][4 * q4 + 2];
      v.w = o[hb][4 * q4 + 3];
      *reinterpret_cast<float4*>(po + (size_t)qrow * 64 + h0) = v;
    }
  if (hi5 == 0) {
    float* pml = part_ml + idx * 256;
    pml[qrow] = m;
    pml[128 + qrow] = lsum;
  }
}

// ---------------- kernel 2b: combine + normalize --------------------------
// grid NB*32 x 256 thr; thread = (row = tid>>1, 32-col half = tid&1)
__global__ __launch_bounds__(256) void k_attn_comb(const float* __restrict__ part_o,
                                                   const float* __restrict__ part_ml,
                                                   float* __restrict__ out,
                                                   int CH, int MAXC) {
  const int gid = blockIdx.x;
  const int s = gid & 31;
  const int b = gid >> 5;
  const int row = threadIdx.x >> 1;
  const int half = threadIdx.x & 1;
  const int ntiles = 2 * s + 2;
  const int nc = (ntiles + CH - 1) / CH;
  const size_t base = (size_t)(b * 32 + s) * MAXC;

  float M = -1e30f;
  for (int c = 0; c < nc; ++c)
    M = fmaxf(M, part_ml[(base + c) * 256 + row]);
  float L = 0.f;
  float4 a[8];
#pragma unroll
  for (int k = 0; k < 8; ++k) a[k] = float4{0, 0, 0, 0};
  for (int c = 0; c < nc; ++c) {
    const float mc = part_ml[(base + c) * 256 + row];
    const float lc = part_ml[(base + c) * 256 + 128 + row];
    const float sc = exp2f(mc - M);
    L += lc * sc;
    const float4* op = reinterpret_cast<const float4*>(
        part_o + (base + c) * (128 * 64) + (size_t)row * 64 + half * 32);
#pragma unroll
    for (int k = 0; k < 8; ++k) {
      const float4 v = op[k];
      a[k].x += v.x * sc; a[k].y += v.y * sc;
      a[k].z += v.z * sc; a[k].w += v.w * sc;
    }
  }
  const float inv = 1.f / L;
  float4* outp = reinterpret_cast<float4*>(
      out + (size_t)(b * NT + s * 128 + row) * NH + half * 32);
#pragma unroll
  for (int k = 0; k < 8; ++k) {
    a[k].x *= inv; a[k].y *= inv; a[k].z *= inv; a[k].w *= inv;
    outp[k] = a[k];
  }
}

// ---------------- launcher ------------------------------------------------
extern "C" void kernel_launch(void* const* d_in, const int* in_sizes, int n_in,
                              void* d_out, int out_size, void* d_ws, size_t ws_size,
                              hipStream_t stream) {
  const float* x  = (const float*)d_in[0];
  const float* Wk = (const float*)d_in[1];
  const float* Wq = (const float*)d_in[2];
  const float* Wv = (const float*)d_in[3];
  float* out = (float*)d_out;

  char* ws = (char*)d_ws;
  const size_t sz_wt  = (size_t)3 * NH * NE * sizeof(bf16);
  const size_t sz_qkv = (size_t)NB * NT * NH * sizeof(bf16);
  const size_t off_q  = (sz_wt + 255) & ~size_t(255);
  const size_t off_k  = off_q + sz_qkv;
  const size_t off_vt = off_k + sz_qkv;
  const size_t off_pp = off_vt + sz_qkv;

  // chunk ladder: pick the largest split the workspace can hold
  const size_t per_chunk = (size_t)(128 * 64 + 256) * sizeof(float);  // 33 KB
  int CH = 64, MAXC = 1;
  const int opts_ch[3]   = {6, 8, 16};
  const int opts_maxc[3] = {11, 8, 4};
  for (int i = 0; i < 3; ++i) {
    const size_t need = off_pp + (size_t)NB * 32 * opts_maxc[i] * per_chunk;
    if (ws_size >= need) { CH = opts_ch[i]; MAXC = opts_maxc[i]; break; }
  }
  const size_t n_idx = (size_t)NB * 32 * MAXC;
  const size_t off_po = off_pp;
  const size_t off_ml = off_po + n_idx * (128 * 64) * sizeof(float);

  bf16* Wt2 = (bf16*)(ws);
  bf16* Qw  = (bf16*)(ws + off_q);
  bf16* Kw  = (bf16*)(ws + off_k);
  bf16* Vtw = (bf16*)(ws + off_vt);
  float* part_o  = (float*)(ws + off_po);
  float* part_ml = (float*)(ws + off_ml);

  hipLaunchKernelGGL(k_wt, dim3(3 * 24), dim3(256), 0, stream, Wk, Wq, Wv, Wt2);
  hipLaunchKernelGGL(k_proj, dim3(NB * NT / 16), dim3(256), 0, stream,
                     x, Wt2, Qw, Kw, Vtw);
  hipLaunchKernelGGL(k_attn_part, dim3(NB * 32 * MAXC), dim3(256), 0, stream,
                     Qw, Kw, Vtw, part_o, part_ml, CH, MAXC);
  hipLaunchKernelGGL(k_attn_comb, dim3(NB * 32), dim3(256), 0, stream,
                     part_o, part_ml, out, CH, MAXC);
}